// Round 7
// baseline (62.705 us; speedup 1.0000x reference)
//
#include <hip/hip_runtime.h>
#include <stdint.h>

#define HW 65536
#define BATCH 64
#define KTOP 200
#define TLOW 16.0f         // candidate pre-filter: P(diff >= 16) ~ 4.6% for 2*chi2(3)
#define TLOW_BITS 0x41800000u
#define K1_BLOCKS 1024     // 16 blocks per batch, 4096 elements per block
#define NSLOT 128          // candidate slots per K1 WAVE (1024 elems/wave, mean ~47, 12 sigma)
#define SLOTS_PER_B 64     // 16 blocks * 4 waves
#define MAXPT 64           // K2 per-lane register values; capacity 64*64=4096 (mean ~3016)

// ---------------------------------------------------------------------------
// Kernel 1: diff + per-wave candidate compaction. No LDS, no barriers, no
// atomics. Each wave owns a private slot region; running count tracked in
// registers via wave-uniform ballot/popcount. Also zeroes out[0] for K2.
// ---------------------------------------------------------------------------
__global__ __launch_bounds__(256) void diff_compact(
    const float* __restrict__ pred,
    const float* __restrict__ target,
    float* __restrict__ cand,        // [K1_BLOCKS*4][NSLOT]
    uint32_t* __restrict__ bcnt,     // [K1_BLOCKS*4]
    float* __restrict__ out)
{
    const int tid  = threadIdx.x;
    const int lane = tid & 63;
    const int wave = tid >> 6;
    const int b    = blockIdx.x >> 4;        // 16 blocks per batch
    const int blk  = blockIdx.x & 15;
    const int slot = blockIdx.x * 4 + wave;  // global wave-slot id

    if (blockIdx.x == 0 && tid == 0) out[0] = 0.0f;   // K2 accumulates into out

    const float4* p = (const float4*)pred;
    const float4* t = (const float4*)target;
    const long bb = (long)b * 49152;         // 3 * 16384 float4 per batch
    float* cs = cand + (long)slot * NSLOT;

    const unsigned long long lmask = (lane == 63) ? ~0ull : ((1ull << (lane + 1)) - 1ull);
    uint32_t wcount = 0;

    #pragma unroll
    for (int chunk = 0; chunk < 4; ++chunk) {
        const int pos = blk * 1024 + chunk * 256 + tid;   // float4 index in batch
        long base = bb + pos;
        float4 p0 = p[base], p1 = p[base + 16384], p2 = p[base + 32768];
        float4 t0 = t[base], t1 = t[base + 16384], t2 = t[base + 32768];

        float d[4];
        {
            float a0 = t0.x - p0.x, a1 = t1.x - p1.x, a2 = t2.x - p2.x;
            d[0] = a0 * a0 + a1 * a1 + a2 * a2;
        }
        {
            float a0 = t0.y - p0.y, a1 = t1.y - p1.y, a2 = t2.y - p2.y;
            d[1] = a0 * a0 + a1 * a1 + a2 * a2;
        }
        {
            float a0 = t0.z - p0.z, a1 = t1.z - p1.z, a2 = t2.z - p2.z;
            d[2] = a0 * a0 + a1 * a1 + a2 * a2;
        }
        {
            float a0 = t0.w - p0.w, a1 = t1.w - p1.w, a2 = t2.w - p2.w;
            d[3] = a0 * a0 + a1 * a1 + a2 * a2;
        }

        #pragma unroll
        for (int j = 0; j < 4; ++j) {
            bool pr = d[j] >= TLOW;
            unsigned long long mask = __ballot(pr);
            if (pr) {
                uint32_t idx = wcount + (uint32_t)__popcll(mask & lmask) - 1u;
                if (idx < NSLOT) cs[idx] = d[j];
            }
            wcount += (uint32_t)__popcll(mask);   // wave-uniform
        }
    }
    if (lane == 0) bcnt[slot] = wcount;           // raw count; >NSLOT -> K2 fallback
}

// ---------------------------------------------------------------------------
// Kernel 2: ONE WAVE per batch. Gather candidates into LDS, pad into 64
// registers/lane, then exact kth-largest via bit-pattern binary search
// (monotone predicate count(v>=m)>=k). No barriers, no LDS atomics.
// Fallback: same binary search streaming recomputed values from global.
// ---------------------------------------------------------------------------
__global__ __launch_bounds__(64) void select_sum(
    const float* __restrict__ cand,      // null -> fallback for all batches
    const uint32_t* __restrict__ bcnt,
    const float* __restrict__ pred,
    const float* __restrict__ target,
    float* __restrict__ out)
{
    __shared__ float cls[MAXPT * 64];    // 16 KB

    const int b    = blockIdx.x;
    const int lane = threadIdx.x;

    // per-slot counts + in-wave exclusive scan
    uint32_t myc = 0;
    if (cand) myc = bcnt[b * SLOTS_PER_B + lane];
    const bool ovf = (__ballot(myc > NSLOT) != 0ull);
    uint32_t scan = myc;
    for (int o = 1; o < 64; o <<= 1) {
        uint32_t v = __shfl_up(scan, o, 64);
        if (lane >= o) scan += v;
    }
    const uint32_t myoff = scan - myc;
    const uint32_t total = __shfl(scan, 63, 64);

    const bool fb = (!cand) || ovf || (total < KTOP) || (total > MAXPT * 64);

    const float* pb = pred   + (long)b * 3 * HW;
    const float* tb = target + (long)b * 3 * HW;

    if (!fb) {
        // ---- gather: slot-sequential, coalesced within each slot ----
        for (int j = 0; j < SLOTS_PER_B; ++j) {
            uint32_t cj  = __shfl(myc, j, 64);
            uint32_t oj  = __shfl(myoff, j, 64);
            const float* src = cand + (long)(b * SLOTS_PER_B + j) * NSLOT;
            for (uint32_t k = lane; k < cj; k += 64)
                cls[oj + k] = src[k];
        }
        // wave-coherent LDS: no barrier needed (single wave), but be safe
        __builtin_amdgcn_s_waitcnt(0);

        // ---- pad into registers, track max ----
        uint32_t u[MAXPT];
        uint32_t mx = 0;
        #pragma unroll
        for (int j = 0; j < MAXPT; ++j) {
            uint32_t idx = lane + j * 64;
            uint32_t v = (idx < total) ? __float_as_uint(cls[idx]) : 0u;
            u[j] = v;
            mx = v > mx ? v : mx;
        }
        for (int o = 32; o > 0; o >>= 1) {
            uint32_t m2 = __shfl_xor(mx, o, 64);
            mx = m2 > mx ? m2 : mx;
        }

        // ---- binary search for exact kth-largest bit pattern ----
        uint32_t lo = TLOW_BITS, hi = mx + 1;    // P(lo)=true: all cands >= TLOW, total >= KTOP
        while (hi - lo > 1) {
            uint32_t mid = lo + ((hi - lo) >> 1);
            uint32_t cnt = 0;
            #pragma unroll
            for (int j = 0; j < MAXPT; ++j) cnt += (u[j] >= mid) ? 1u : 0u;
            for (int o = 32; o > 0; o >>= 1) cnt += __shfl_xor(cnt, o, 64);
            if (cnt >= KTOP) lo = mid; else hi = mid;   // wave-uniform
        }
        const uint32_t T = lo;

        // ---- sum of top-KTOP with tie handling ----
        float    s = 0.0f;
        uint32_t c = 0;
        #pragma unroll
        for (int j = 0; j < MAXPT; ++j) {
            if (u[j] > T) { s += __uint_as_float(u[j]); c += 1u; }
        }
        for (int o = 32; o > 0; o >>= 1) {
            s += __shfl_xor(s, o, 64);
            c += __shfl_xor(c, o, 64);
        }
        if (lane == 0) {
            float partial = s + (float)(KTOP - c) * __uint_as_float(T);
            atomicAdd(out, partial * (1.0f / (float)(BATCH * KTOP)));
        }
        return;
    }

    // ---------------- fallback: exact, streams full row (never hot) --------
    auto getd = [&](uint32_t idx) -> float {
        float a0 = tb[idx] - pb[idx];
        float a1 = tb[HW + idx] - pb[HW + idx];
        float a2 = tb[2 * HW + idx] - pb[2 * HW + idx];
        return a0 * a0 + a1 * a1 + a2 * a2;
    };
    uint32_t mx = 0;
    for (uint32_t i = lane; i < HW; i += 64) {
        uint32_t v = __float_as_uint(getd(i));
        mx = v > mx ? v : mx;
    }
    for (int o = 32; o > 0; o >>= 1) {
        uint32_t m2 = __shfl_xor(mx, o, 64);
        mx = m2 > mx ? m2 : mx;
    }
    uint32_t lo = 0, hi = mx + 1;                // P(0): count >= HW >= KTOP
    while (hi - lo > 1) {
        uint32_t mid = lo + ((hi - lo) >> 1);
        uint32_t cnt = 0;
        for (uint32_t i = lane; i < HW; i += 64)
            cnt += (__float_as_uint(getd(i)) >= mid) ? 1u : 0u;
        for (int o = 32; o > 0; o >>= 1) cnt += __shfl_xor(cnt, o, 64);
        if (cnt >= KTOP) lo = mid; else hi = mid;
    }
    const uint32_t T = lo;
    float    s = 0.0f;
    uint32_t c = 0;
    for (uint32_t i = lane; i < HW; i += 64) {
        uint32_t v = __float_as_uint(getd(i));
        if (v > T) { s += __uint_as_float(v); c += 1u; }
    }
    for (int o = 32; o > 0; o >>= 1) {
        s += __shfl_xor(s, o, 64);
        c += __shfl_xor(c, o, 64);
    }
    if (lane == 0) {
        float partial = s + (float)(KTOP - c) * __uint_as_float(T);
        atomicAdd(out, partial * (1.0f / (float)(BATCH * KTOP)));
    }
}

// tiny init for the ws-too-small path (select_sum fallback needs out=0)
__global__ void zero_out(float* __restrict__ out) { out[0] = 0.0f; }

extern "C" void kernel_launch(void* const* d_in, const int* in_sizes, int n_in,
                              void* d_out, int out_size, void* d_ws, size_t ws_size,
                              hipStream_t stream)
{
    const float* pred   = (const float*)d_in[0];
    const float* target = (const float*)d_in[1];
    float* out = (float*)d_out;

    const int nslots = K1_BLOCKS * 4;                       // 4096
    uint32_t* bcnt = (uint32_t*)d_ws;                       // 16 KB
    float*    cand = (float*)((char*)d_ws + nslots * 4);    // 2 MB
    const size_t need = (size_t)nslots * 4 + (size_t)nslots * NSLOT * 4;

    if (ws_size >= need) {
        diff_compact<<<K1_BLOCKS, 256, 0, stream>>>(pred, target, cand, bcnt, out);
        select_sum<<<BATCH, 64, 0, stream>>>(cand, bcnt, pred, target, out);
    } else {
        zero_out<<<1, 1, 0, stream>>>(out);
        select_sum<<<BATCH, 64, 0, stream>>>(nullptr, nullptr, pred, target, out);
    }
}

// Round 8
// 40.254 us; speedup vs baseline: 1.5577x; 1.5577x over previous
//
#include <hip/hip_runtime.h>
#include <stdint.h>

#define HW 65536
#define BATCH 64
#define KTOP 200
#define TLOW 16.0f         // candidate pre-filter: P(diff >= 16) ~ 4.6% for 2*chi2(3)
#define TLOW_BITS 0x41800000u
#define K1_BLOCKS 1024     // 16 blocks per batch, 4096 elements per block
#define NSLOT 128          // candidate slots per K1 WAVE (1024 elems/wave, mean ~47, 12 sigma)
#define SLOTS_PER_B 64     // 16 blocks * 4 waves
#define VPT16 16           // K2 register values per thread (256 thr): cap 4096 (mean ~3016)
#define MAXITER 32

// ---------------------------------------------------------------------------
// Kernel 1: diff + per-wave candidate compaction. No LDS, no barriers, no
// atomics. Each wave owns a private slot region; running count tracked in
// registers via wave-uniform ballot/popcount. Also zeroes out[0] for K2.
// ---------------------------------------------------------------------------
__global__ __launch_bounds__(256) void diff_compact(
    const float* __restrict__ pred,
    const float* __restrict__ target,
    float* __restrict__ cand,        // [K1_BLOCKS*4][NSLOT]
    uint32_t* __restrict__ bcnt,     // [K1_BLOCKS*4]
    float* __restrict__ out)
{
    const int tid  = threadIdx.x;
    const int lane = tid & 63;
    const int wave = tid >> 6;
    const int b    = blockIdx.x >> 4;        // 16 blocks per batch
    const int blk  = blockIdx.x & 15;
    const int slot = blockIdx.x * 4 + wave;  // global wave-slot id

    if (blockIdx.x == 0 && tid == 0) out[0] = 0.0f;   // K2 accumulates into out

    const float4* p = (const float4*)pred;
    const float4* t = (const float4*)target;
    const long bb = (long)b * 49152;         // 3 * 16384 float4 per batch
    float* cs = cand + (long)slot * NSLOT;

    const unsigned long long lmask = (lane == 63) ? ~0ull : ((1ull << (lane + 1)) - 1ull);
    uint32_t wcount = 0;

    #pragma unroll
    for (int chunk = 0; chunk < 4; ++chunk) {
        const int pos = blk * 1024 + chunk * 256 + tid;   // float4 index in batch
        long base = bb + pos;
        float4 p0 = p[base], p1 = p[base + 16384], p2 = p[base + 32768];
        float4 t0 = t[base], t1 = t[base + 16384], t2 = t[base + 32768];

        float d[4];
        {
            float a0 = t0.x - p0.x, a1 = t1.x - p1.x, a2 = t2.x - p2.x;
            d[0] = a0 * a0 + a1 * a1 + a2 * a2;
        }
        {
            float a0 = t0.y - p0.y, a1 = t1.y - p1.y, a2 = t2.y - p2.y;
            d[1] = a0 * a0 + a1 * a1 + a2 * a2;
        }
        {
            float a0 = t0.z - p0.z, a1 = t1.z - p1.z, a2 = t2.z - p2.z;
            d[2] = a0 * a0 + a1 * a1 + a2 * a2;
        }
        {
            float a0 = t0.w - p0.w, a1 = t1.w - p1.w, a2 = t2.w - p2.w;
            d[3] = a0 * a0 + a1 * a1 + a2 * a2;
        }

        #pragma unroll
        for (int j = 0; j < 4; ++j) {
            bool pr = d[j] >= TLOW;
            unsigned long long mask = __ballot(pr);
            if (pr) {
                uint32_t idx = wcount + (uint32_t)__popcll(mask & lmask) - 1u;
                if (idx < NSLOT) cs[idx] = d[j];
            }
            wcount += (uint32_t)__popcll(mask);   // wave-uniform
        }
    }
    if (lane == 0) bcnt[slot] = wcount;           // raw count; >NSLOT -> K2 fallback
}

// ---------------------------------------------------------------------------
// Kernel 2: one block (256 thr) per batch. Gather candidates into LDS, pad
// 16 values/thread into REGISTERS (fully-unrolled static indexing -> no
// scratch), exact kth-largest via bit-pattern binary search (monotone
// predicate count(v>=m)>=k), sum + tie handling.
// Fallback: streaming binary search over recomputed full row (exact).
// ---------------------------------------------------------------------------
__global__ __launch_bounds__(256) void select_sum(
    const float* __restrict__ cand,      // null -> fallback for all batches
    const uint32_t* __restrict__ bcnt,
    const float* __restrict__ pred,
    const float* __restrict__ target,
    float* __restrict__ out)
{
    __shared__ float    cls[VPT16 * 256];   // 16 KB
    __shared__ uint32_t scounts[64];
    __shared__ uint32_t soff[64];
    __shared__ uint32_t meta[2];
    __shared__ uint32_t xw[MAXITER][4];     // per-iteration cross-wave slots
    __shared__ uint32_t mxw[4];
    __shared__ float    wsumS[4];
    __shared__ uint32_t wcntS[4];

    const int b    = blockIdx.x;
    const int tid  = threadIdx.x;
    const int lane = tid & 63;
    const int wave = tid >> 6;

    // ---- per-slot counts + wave-0 exclusive scan ----
    if (tid < 64) {
        uint32_t c = cand ? bcnt[b * SLOTS_PER_B + tid] : 0u;
        scounts[tid] = c;
        uint32_t scan = c;
        for (int o = 1; o < 64; o <<= 1) {
            uint32_t v = __shfl_up(scan, o, 64);
            if (lane >= o) scan += v;
        }
        soff[tid] = scan - c;
        if (tid == 63) meta[0] = scan;
        uint32_t ovf = (__ballot(c > NSLOT) != 0ull) ? 1u : 0u;
        if (tid == 0) meta[1] = cand ? ovf : 1u;
    }
    __syncthreads();

    const uint32_t total = meta[0];
    const bool fb = (meta[1] != 0) || (total < KTOP) || (total > VPT16 * 256);

    const float* pb = pred   + (long)b * 3 * HW;
    const float* tb = target + (long)b * 3 * HW;

    if (!fb) {
        // ---- gather into LDS (wave w handles slots w, w+4, ...) ----
        for (int j = wave; j < SLOTS_PER_B; j += 4) {
            uint32_t cj  = scounts[j];
            uint32_t oj  = soff[j];
            const float* src = cand + (long)(b * SLOTS_PER_B + j) * NSLOT;
            for (uint32_t k = lane; k < cj; k += 64)
                cls[oj + k] = src[k];
        }
        __syncthreads();

        // ---- 16 values/thread into registers (static indices only) ----
        uint32_t u[VPT16];
        uint32_t mx = 0;
        #pragma unroll
        for (int j = 0; j < VPT16; ++j) {
            uint32_t idx = tid + j * 256;
            uint32_t v = (idx < total) ? __float_as_uint(cls[idx]) : 0u;
            u[j] = v;
            mx = v > mx ? v : mx;
        }
        for (int o = 32; o > 0; o >>= 1) {
            uint32_t m2 = __shfl_xor(mx, o, 64);
            mx = m2 > mx ? m2 : mx;
        }
        if (lane == 0) mxw[wave] = mx;
        __syncthreads();
        mx = mxw[0];
        #pragma unroll
        for (int w = 1; w < 4; ++w) mx = mxw[w] > mx ? mxw[w] : mx;

        // ---- binary search for exact kth-largest bit pattern ----
        uint32_t lo = TLOW_BITS, hi = mx + 1;   // P(lo)=true: all cands >= TLOW, total >= KTOP
        int it = 0;
        while (hi - lo > 1 && it < MAXITER) {
            uint32_t mid = lo + ((hi - lo) >> 1);
            uint32_t cnt = 0;
            #pragma unroll
            for (int j = 0; j < VPT16; ++j) cnt += (u[j] >= mid) ? 1u : 0u;
            for (int o = 32; o > 0; o >>= 1) cnt += __shfl_xor(cnt, o, 64);
            if (lane == 0) xw[it][wave] = cnt;
            __syncthreads();
            cnt = xw[it][0] + xw[it][1] + xw[it][2] + xw[it][3];
            if (cnt >= KTOP) lo = mid; else hi = mid;    // block-uniform
            ++it;
        }
        const uint32_t T = lo;

        // ---- sum of top-KTOP with tie handling ----
        float    s = 0.0f;
        uint32_t c = 0;
        #pragma unroll
        for (int j = 0; j < VPT16; ++j) {
            if (u[j] > T) { s += __uint_as_float(u[j]); c += 1u; }
        }
        for (int o = 32; o > 0; o >>= 1) {
            s += __shfl_xor(s, o, 64);
            c += __shfl_xor(c, o, 64);
        }
        if (lane == 0) { wsumS[wave] = s; wcntS[wave] = c; }
        __syncthreads();
        if (tid == 0) {
            float    S = 0.0f;
            uint32_t C = 0;
            #pragma unroll
            for (int w = 0; w < 4; ++w) { S += wsumS[w]; C += wcntS[w]; }
            float partial = S + (float)(KTOP - C) * __uint_as_float(T);
            atomicAdd(out, partial * (1.0f / (float)(BATCH * KTOP)));
        }
        return;
    }

    // ---------------- fallback: exact, streams full row (never hot) --------
    auto getd = [&](uint32_t idx) -> float {
        float a0 = tb[idx] - pb[idx];
        float a1 = tb[HW + idx] - pb[HW + idx];
        float a2 = tb[2 * HW + idx] - pb[2 * HW + idx];
        return a0 * a0 + a1 * a1 + a2 * a2;
    };
    uint32_t mx = 0;
    for (uint32_t i = tid; i < HW; i += 256) {
        uint32_t v = __float_as_uint(getd(i));
        mx = v > mx ? v : mx;
    }
    for (int o = 32; o > 0; o >>= 1) {
        uint32_t m2 = __shfl_xor(mx, o, 64);
        mx = m2 > mx ? m2 : mx;
    }
    if (lane == 0) mxw[wave] = mx;
    __syncthreads();
    mx = mxw[0];
    #pragma unroll
    for (int w = 1; w < 4; ++w) mx = mxw[w] > mx ? mxw[w] : mx;

    uint32_t lo = 0, hi = mx + 1;
    int it = 0;
    while (hi - lo > 1 && it < MAXITER) {
        uint32_t mid = lo + ((hi - lo) >> 1);
        uint32_t cnt = 0;
        for (uint32_t i = tid; i < HW; i += 256)
            cnt += (__float_as_uint(getd(i)) >= mid) ? 1u : 0u;
        for (int o = 32; o > 0; o >>= 1) cnt += __shfl_xor(cnt, o, 64);
        if (lane == 0) xw[it][wave] = cnt;
        __syncthreads();
        cnt = xw[it][0] + xw[it][1] + xw[it][2] + xw[it][3];
        if (cnt >= KTOP) lo = mid; else hi = mid;
        ++it;
    }
    const uint32_t T = lo;
    float    s = 0.0f;
    uint32_t c = 0;
    for (uint32_t i = tid; i < HW; i += 256) {
        uint32_t v = __float_as_uint(getd(i));
        if (v > T) { s += __uint_as_float(v); c += 1u; }
    }
    for (int o = 32; o > 0; o >>= 1) {
        s += __shfl_xor(s, o, 64);
        c += __shfl_xor(c, o, 64);
    }
    if (lane == 0) { wsumS[wave] = s; wcntS[wave] = c; }
    __syncthreads();
    if (tid == 0) {
        float    S = 0.0f;
        uint32_t C = 0;
        #pragma unroll
        for (int w = 0; w < 4; ++w) { S += wsumS[w]; C += wcntS[w]; }
        float partial = S + (float)(KTOP - C) * __uint_as_float(T);
        atomicAdd(out, partial * (1.0f / (float)(BATCH * KTOP)));
    }
}

// tiny init for the ws-too-small path (select_sum fallback needs out=0)
__global__ void zero_out(float* __restrict__ out) { out[0] = 0.0f; }

extern "C" void kernel_launch(void* const* d_in, const int* in_sizes, int n_in,
                              void* d_out, int out_size, void* d_ws, size_t ws_size,
                              hipStream_t stream)
{
    const float* pred   = (const float*)d_in[0];
    const float* target = (const float*)d_in[1];
    float* out = (float*)d_out;

    const int nslots = K1_BLOCKS * 4;                       // 4096
    uint32_t* bcnt = (uint32_t*)d_ws;                       // 16 KB
    float*    cand = (float*)((char*)d_ws + nslots * 4);    // 2 MB
    const size_t need = (size_t)nslots * 4 + (size_t)nslots * NSLOT * 4;

    if (ws_size >= need) {
        diff_compact<<<K1_BLOCKS, 256, 0, stream>>>(pred, target, cand, bcnt, out);
        select_sum<<<BATCH, 256, 0, stream>>>(cand, bcnt, pred, target, out);
    } else {
        zero_out<<<1, 1, 0, stream>>>(out);
        select_sum<<<BATCH, 256, 0, stream>>>(nullptr, nullptr, pred, target, out);
    }
}

// Round 9
// 37.066 us; speedup vs baseline: 1.6917x; 1.0860x over previous
//
#include <hip/hip_runtime.h>
#include <stdint.h>

#define HW 65536
#define BATCH 64
#define KTOP 200
#define TLOW 16.0f         // candidate pre-filter: P(diff >= 16) ~ 4.6% for 2*chi2(3)
#define TLOW_BITS 0x41800000u
#define K1_BLOCKS 1024     // 16 blocks per batch, 4096 elements per block
#define NSLOT 128          // candidate slots per K1 WAVE (1024 elems/wave, mean ~47, 12 sigma)
#define SLOTS_PER_B 64     // 16 blocks * 4 waves
#define VPT32 32           // K2: 32 register values/thread x 256 thr = 8192 = 64*128 (full slot array)

// ---------------------------------------------------------------------------
// Kernel 1: diff + per-wave candidate compaction. No LDS, no barriers, no
// atomics. Each wave owns a private slot region; running count tracked in
// registers via wave-uniform ballot/popcount. Also zeroes out[0] for K2.
// ---------------------------------------------------------------------------
__global__ __launch_bounds__(256) void diff_compact(
    const float* __restrict__ pred,
    const float* __restrict__ target,
    float* __restrict__ cand,        // [K1_BLOCKS*4][NSLOT]
    uint32_t* __restrict__ bcnt,     // [K1_BLOCKS*4]
    float* __restrict__ out)
{
    const int tid  = threadIdx.x;
    const int lane = tid & 63;
    const int wave = tid >> 6;
    const int b    = blockIdx.x >> 4;        // 16 blocks per batch
    const int blk  = blockIdx.x & 15;
    const int slot = blockIdx.x * 4 + wave;  // global wave-slot id

    if (blockIdx.x == 0 && tid == 0) out[0] = 0.0f;   // K2 accumulates into out

    const float4* p = (const float4*)pred;
    const float4* t = (const float4*)target;
    const long bb = (long)b * 49152;         // 3 * 16384 float4 per batch
    float* cs = cand + (long)slot * NSLOT;

    const unsigned long long lmask = (lane == 63) ? ~0ull : ((1ull << (lane + 1)) - 1ull);
    uint32_t wcount = 0;

    #pragma unroll
    for (int chunk = 0; chunk < 4; ++chunk) {
        const int pos = blk * 1024 + chunk * 256 + tid;   // float4 index in batch
        long base = bb + pos;
        float4 p0 = p[base], p1 = p[base + 16384], p2 = p[base + 32768];
        float4 t0 = t[base], t1 = t[base + 16384], t2 = t[base + 32768];

        float d[4];
        {
            float a0 = t0.x - p0.x, a1 = t1.x - p1.x, a2 = t2.x - p2.x;
            d[0] = a0 * a0 + a1 * a1 + a2 * a2;
        }
        {
            float a0 = t0.y - p0.y, a1 = t1.y - p1.y, a2 = t2.y - p2.y;
            d[1] = a0 * a0 + a1 * a1 + a2 * a2;
        }
        {
            float a0 = t0.z - p0.z, a1 = t1.z - p1.z, a2 = t2.z - p2.z;
            d[2] = a0 * a0 + a1 * a1 + a2 * a2;
        }
        {
            float a0 = t0.w - p0.w, a1 = t1.w - p1.w, a2 = t2.w - p2.w;
            d[3] = a0 * a0 + a1 * a1 + a2 * a2;
        }

        #pragma unroll
        for (int j = 0; j < 4; ++j) {
            bool pr = d[j] >= TLOW;
            unsigned long long mask = __ballot(pr);
            if (pr) {
                uint32_t idx = wcount + (uint32_t)__popcll(mask & lmask) - 1u;
                if (idx < NSLOT) cs[idx] = d[j];
            }
            wcount += (uint32_t)__popcll(mask);   // wave-uniform
        }
    }
    if (lane == 0) bcnt[slot] = wcount;           // raw count; >NSLOT -> K2 fallback
}

// ---------------------------------------------------------------------------
// Kernel 2: one block (256 thr) per batch. FLAT gather: every thread loads 8
// unconditional coalesced float4 from the fixed-stride [64][128] slot array
// straight into u[32] registers (static indices only), masking validity by
// k < cnt[slot]. Exact kth-largest via bit-pattern binary search, then
// top-KTOP sum with tie handling. Fallback: streaming over recomputed row.
// ---------------------------------------------------------------------------
__global__ __launch_bounds__(256) void select_sum(
    const float* __restrict__ cand,      // null -> fallback for all batches
    const uint32_t* __restrict__ bcnt,
    const float* __restrict__ pred,
    const float* __restrict__ target,
    float* __restrict__ out)
{
    __shared__ uint32_t scnt_s[64];
    __shared__ uint32_t meta[2];         // {total, fb-flag}
    __shared__ uint32_t xa[4];
    __shared__ uint32_t mxw[4];
    __shared__ float    wsumS[4];
    __shared__ uint32_t wcntS[4];

    const int b    = blockIdx.x;
    const int tid  = threadIdx.x;
    const int lane = tid & 63;
    const int wave = tid >> 6;

    // ---- per-slot counts: stage to LDS + wave-0 total/overflow ----
    if (tid < 64) {
        uint32_t c = cand ? bcnt[b * SLOTS_PER_B + tid] : 0u;
        scnt_s[tid] = c;
        uint32_t tot = c;
        for (int o = 32; o > 0; o >>= 1) tot += __shfl_xor(tot, o, 64);
        bool anyovf = (__ballot(c > NSLOT) != 0ull);
        if (tid == 0) {
            meta[0] = tot;
            meta[1] = (cand && !anyovf) ? 0u : 1u;
        }
    }
    __syncthreads();

    const uint32_t total = meta[0];
    const bool fb = (meta[1] != 0) || (total < KTOP);

    const float* pb = pred   + (long)b * 3 * HW;
    const float* tb = target + (long)b * 3 * HW;

    if (!fb) {
        // ---- flat unconditional gather: 8 coalesced float4/thread ----
        const float4* c4 = (const float4*)(cand + (long)b * SLOTS_PER_B * NSLOT);
        const int s0 = tid >> 5;          // sub-slot index within each 1024-elem chunk
        const int k  = (tid & 31) * 4;    // element offset within the 128-elem slot
        uint32_t u[VPT32];
        #pragma unroll
        for (int j = 0; j < 8; ++j) {
            float4 v = c4[j * 256 + tid];             // chunk j: elems [j*1024, j*1024+1024)
            uint32_t cs = scnt_s[j * 8 + s0];         // slot of this float4 (uniform per f4)
            u[j * 4 + 0] = (uint32_t)(k + 0) < cs ? __float_as_uint(v.x) : 0u;
            u[j * 4 + 1] = (uint32_t)(k + 1) < cs ? __float_as_uint(v.y) : 0u;
            u[j * 4 + 2] = (uint32_t)(k + 2) < cs ? __float_as_uint(v.z) : 0u;
            u[j * 4 + 3] = (uint32_t)(k + 3) < cs ? __float_as_uint(v.w) : 0u;
        }

        // ---- block max (search upper bound) ----
        uint32_t mx = 0;
        #pragma unroll
        for (int j = 0; j < VPT32; ++j) mx = u[j] > mx ? u[j] : mx;
        for (int o = 32; o > 0; o >>= 1) {
            uint32_t m2 = __shfl_xor(mx, o, 64);
            mx = m2 > mx ? m2 : mx;
        }
        if (lane == 0) mxw[wave] = mx;
        __syncthreads();
        mx = mxw[0];
        #pragma unroll
        for (int w = 1; w < 4; ++w) mx = mxw[w] > mx ? mxw[w] : mx;

        // ---- binary search for exact kth-largest bit pattern ----
        // invariant: count(>= lo) >= KTOP (lo=TLOW_BITS: all candidates, total>=KTOP)
        //            count(>= hi) <  KTOP (hi=mx+1: zero)
        uint32_t lo = TLOW_BITS, hi = mx + 1;
        while (hi - lo > 1) {
            uint32_t mid = lo + ((hi - lo) >> 1);
            uint32_t cnt = 0;
            #pragma unroll
            for (int j = 0; j < VPT32; ++j) cnt += (u[j] >= mid) ? 1u : 0u;
            for (int o = 32; o > 0; o >>= 1) cnt += __shfl_xor(cnt, o, 64);
            if (lane == 0) xa[wave] = cnt;
            __syncthreads();
            cnt = xa[0] + xa[1] + xa[2] + xa[3];
            __syncthreads();                           // protect xa before next write
            if (cnt >= KTOP) lo = mid; else hi = mid;  // block-uniform
        }
        const uint32_t T = lo;

        // ---- sum of top-KTOP with tie handling ----
        float    s = 0.0f;
        uint32_t c = 0;
        #pragma unroll
        for (int j = 0; j < VPT32; ++j) {
            if (u[j] > T) { s += __uint_as_float(u[j]); c += 1u; }
        }
        for (int o = 32; o > 0; o >>= 1) {
            s += __shfl_xor(s, o, 64);
            c += __shfl_xor(c, o, 64);
        }
        if (lane == 0) { wsumS[wave] = s; wcntS[wave] = c; }
        __syncthreads();
        if (tid == 0) {
            float    S = 0.0f;
            uint32_t C = 0;
            #pragma unroll
            for (int w = 0; w < 4; ++w) { S += wsumS[w]; C += wcntS[w]; }
            float partial = S + (float)(KTOP - C) * __uint_as_float(T);
            atomicAdd(out, partial * (1.0f / (float)(BATCH * KTOP)));
        }
        return;
    }

    // ---------------- fallback: exact, streams full row (never hot) --------
    auto getd = [&](uint32_t idx) -> float {
        float a0 = tb[idx] - pb[idx];
        float a1 = tb[HW + idx] - pb[HW + idx];
        float a2 = tb[2 * HW + idx] - pb[2 * HW + idx];
        return a0 * a0 + a1 * a1 + a2 * a2;
    };
    uint32_t mx = 0;
    for (uint32_t i = tid; i < HW; i += 256) {
        uint32_t v = __float_as_uint(getd(i));
        mx = v > mx ? v : mx;
    }
    for (int o = 32; o > 0; o >>= 1) {
        uint32_t m2 = __shfl_xor(mx, o, 64);
        mx = m2 > mx ? m2 : mx;
    }
    if (lane == 0) mxw[wave] = mx;
    __syncthreads();
    mx = mxw[0];
    #pragma unroll
    for (int w = 1; w < 4; ++w) mx = mxw[w] > mx ? mxw[w] : mx;

    uint32_t lo = 0, hi = mx + 1;
    while (hi - lo > 1) {
        uint32_t mid = lo + ((hi - lo) >> 1);
        uint32_t cnt = 0;
        for (uint32_t i = tid; i < HW; i += 256)
            cnt += (__float_as_uint(getd(i)) >= mid) ? 1u : 0u;
        for (int o = 32; o > 0; o >>= 1) cnt += __shfl_xor(cnt, o, 64);
        if (lane == 0) xa[wave] = cnt;
        __syncthreads();
        cnt = xa[0] + xa[1] + xa[2] + xa[3];
        __syncthreads();
        if (cnt >= KTOP) lo = mid; else hi = mid;
    }
    const uint32_t T = lo;
    float    s = 0.0f;
    uint32_t c = 0;
    for (uint32_t i = tid; i < HW; i += 256) {
        uint32_t v = __float_as_uint(getd(i));
        if (v > T) { s += __uint_as_float(v); c += 1u; }
    }
    for (int o = 32; o > 0; o >>= 1) {
        s += __shfl_xor(s, o, 64);
        c += __shfl_xor(c, o, 64);
    }
    if (lane == 0) { wsumS[wave] = s; wcntS[wave] = c; }
    __syncthreads();
    if (tid == 0) {
        float    S = 0.0f;
        uint32_t C = 0;
        #pragma unroll
        for (int w = 0; w < 4; ++w) { S += wsumS[w]; C += wcntS[w]; }
        float partial = S + (float)(KTOP - C) * __uint_as_float(T);
        atomicAdd(out, partial * (1.0f / (float)(BATCH * KTOP)));
    }
}

// tiny init for the ws-too-small path (select_sum fallback needs out=0)
__global__ void zero_out(float* __restrict__ out) { out[0] = 0.0f; }

extern "C" void kernel_launch(void* const* d_in, const int* in_sizes, int n_in,
                              void* d_out, int out_size, void* d_ws, size_t ws_size,
                              hipStream_t stream)
{
    const float* pred   = (const float*)d_in[0];
    const float* target = (const float*)d_in[1];
    float* out = (float*)d_out;

    const int nslots = K1_BLOCKS * 4;                       // 4096
    uint32_t* bcnt = (uint32_t*)d_ws;                       // 16 KB
    float*    cand = (float*)((char*)d_ws + nslots * 4);    // 2 MB
    const size_t need = (size_t)nslots * 4 + (size_t)nslots * NSLOT * 4;

    if (ws_size >= need) {
        diff_compact<<<K1_BLOCKS, 256, 0, stream>>>(pred, target, cand, bcnt, out);
        select_sum<<<BATCH, 256, 0, stream>>>(cand, bcnt, pred, target, out);
    } else {
        zero_out<<<1, 1, 0, stream>>>(out);
        select_sum<<<BATCH, 256, 0, stream>>>(nullptr, nullptr, pred, target, out);
    }
}